// Round 1
// baseline (250.238 us; speedup 1.0000x reference)
//
#include <hip/hip_runtime.h>
#include <hip/hip_bf16.h>
#include <stdint.h>

// Problem constants (from reference)
#define B_ 8
#define T_ 1500
#define H_ 1280
#define HM1 1279
#define OUT_ 4096
#define MTOK 375
#define MROWS (B_*MTOK)   // 3000
#define KPAD 1280         // shared K for both GEMMs (cif K=1279 zero-padded)

typedef __attribute__((ext_vector_type(8))) short bf16x8;  // 8 bf16 = 4 VGPRs
typedef __attribute__((ext_vector_type(4))) float f32x4;
typedef unsigned short u16;

static __device__ __forceinline__ u16 f2bf(float f) {
    unsigned int x = __float_as_uint(f);
    unsigned int r = (x + 0x7fffu + ((x >> 16) & 1u)) >> 16;
    return (u16)r;
}
static __device__ __forceinline__ void glds16(const u16* g, u16* l) {
    __builtin_amdgcn_global_load_lds(
        (const __attribute__((address_space(1))) void*)g,
        (__attribute__((address_space(3))) void*)l, 16, 0, 0);
}

// Front kernel: blocks 0..7 = fused sigmoid+scan+post-pass (one per batch);
// blocks 8.. = both weight transposes (text transpose folds in rms_w).
__global__ __launch_bounds__(256) void k_front(
    const float* __restrict__ audio, const int* __restrict__ num_tokens,
    const float* __restrict__ rms_w,
    float* __restrict__ pred_out,
    int* __restrict__ tok0, float* __restrict__ w0a,
    int* __restrict__ tok1, float* __restrict__ w1a,
    int* __restrict__ lo, int* __restrict__ hi,
    float* __restrict__ h_sumsq,
    const float* __restrict__ cif_w, const float* __restrict__ text_w,
    u16* __restrict__ cwt, u16* __restrict__ twt)
{
    __shared__ float smem[3514];   // union: scan(3513 floats) / transpose tile(32x33)
    const int tid = threadIdx.x;

    if (blockIdx.x < B_) {
        // ================= CIF scan branch =================
        const int b = blockIdx.x;
        float* al = smem;                    // [1500]
        float* ip = smem + 1500;             // [1500]
        float* red = smem + 3000;            // [256]
        int*   redI = (int*)(smem + 3256);   // [256]
        float* scale_sh = smem + 3512;

        // phase 1: sigmoid + pred + scale
        float sig[6];
        float s = 0.f;
        #pragma unroll
        for (int i = 0; i < 6; ++i) {
            int t = tid + i*256;
            sig[i] = 0.f;
            if (t < T_) {
                float x = audio[((size_t)b*T_ + t)*H_ + (H_-1)];
                sig[i] = 1.f / (1.f + expf(-x));
                s += sig[i];
            }
        }
        red[tid] = s; __syncthreads();
        for (int off = 128; off > 0; off >>= 1) {
            if (tid < off) red[tid] += red[tid+off];
            __syncthreads();
        }
        if (tid == 0) {
            float pred = red[0];
            pred_out[b] = pred;
            *scale_sh = (float)num_tokens[b] / pred;
        }
        __syncthreads();
        float scale = *scale_sh;
        #pragma unroll
        for (int i = 0; i < 6; ++i) {
            int t = tid + i*256;
            if (t < T_) al[t] = sig[i] * scale;
        }
        for (int m = tid; m < MTOK; m += 256) {
            lo[b*MTOK+m] = T_; hi[b*MTOK+m] = 0;
            h_sumsq[b*MTOK+m] = 0.f;         // zero for cif-epilogue atomics
        }
        if (tid == 0) lo[b*MTOK] = 0;
        __syncthreads();

        // phase 2: serial carry chain (lane 0), LDS-only emissions
        if (tid == 0) {
            float integ = 0.f;
            float4 cur = *(const float4*)&al[0];
            for (int t = 0; t < T_; t += 4) {
                float4 nxt = (t + 4 < T_) ? *(const float4*)&al[t+4]
                                          : make_float4(0.f,0.f,0.f,0.f);
                float av[4] = {cur.x, cur.y, cur.z, cur.w};
                float ipv[4];
                #pragma unroll
                for (int j = 0; j < 4; ++j) {
                    ipv[j] = integ;
                    float sx = integ + av[j];
                    integ = (sx >= 1.f) ? (sx - 1.f) : sx;
                }
                *(float4*)&ip[t] = *(float4*)ipv;
                cur = nxt;
            }
        }
        __syncthreads();

        // phase 3: parallel post-pass
        const int t0 = tid * 6;
        const int nm1 = num_tokens[b] - 1;
        int fires[6];
        int cnt = 0;
        if (t0 < T_) {
            #pragma unroll
            for (int j = 0; j < 6; ++j) {
                int t = t0 + j;
                float sx = ip[t] + al[t];     // same fp32 add as serial scan
                fires[j] = (sx >= 1.f) ? 1 : 0;
                cnt += fires[j];
            }
        }
        redI[tid] = cnt; __syncthreads();
        #pragma unroll
        for (int off = 1; off < 256; off <<= 1) {
            int v = redI[tid];
            if (tid >= off) v += redI[tid - off];
            __syncthreads();
            redI[tid] = v;
            __syncthreads();
        }
        if (t0 < T_) {
            int F = redI[tid] - cnt;
            const int base = b*T_;
            #pragma unroll
            for (int j = 0; j < 6; ++j) {
                int t = t0 + j;
                float a = al[t], ipv = ip[t];
                int fire = fires[j];
                F += fire;
                int tk1 = min(F, nm1);
                int tk0 = min(F - fire, nm1);
                float w0 = fire ? (1.f - ipv) : a;
                float w1 = (t < T_-1) ? (a - w0) : 0.f;
                tok0[base+t] = tk0;  w0a[base+t] = w0;
                tok1[base+t] = tk1;  w1a[base+t] = w1;
                if (tk1 != tk0) {
                    hi[b*MTOK + tk0] = t + 1;
                    lo[b*MTOK + tk1] = t;
                }
                if (t == T_-1) hi[b*MTOK + tk1] = T_;
            }
        }
    } else {
        // ================= transpose branch =================
        float (*tile)[33] = (float(*)[33])smem;
        int blk = blockIdx.x - B_;
        const float* src; u16* dst; int R, C, bx, by; bool scaled;
        if (blk < 1600) { src = cif_w;  dst = cwt; R = HM1; C = H_;   bx = blk % 40;  by = blk / 40;  scaled = false; }
        else { blk -= 1600; src = text_w; dst = twt; R = H_;  C = OUT_; bx = blk % 128; by = blk / 128; scaled = true; }
        int c0 = bx * 32, r0 = by * 32;
        int lx = tid & 31, ly = tid >> 5;  // 32 x 8
        #pragma unroll
        for (int j = 0; j < 4; ++j) {
            int r = r0 + ly + j*8;
            tile[ly + j*8][lx] = (r < R) ? src[(size_t)r*C + c0 + lx] : 0.f;
        }
        __syncthreads();
        // write value = src[r0+lx][c0+ly+j*8]; its k-index is r0+lx -> fold rms_w
        float rw = scaled ? rms_w[r0 + lx] : 1.f;
        #pragma unroll
        for (int j = 0; j < 4; ++j) {
            int c = c0 + ly + j*8;
            dst[(size_t)c*KPAD + r0 + lx] = f2bf(tile[lx][ly + j*8] * rw);
        }
    }
}

// K3: sparse pooling -> h1b bf16 [MROWS][KPAD], col 1279 = 0.
// Latency-optimized: weights staged to LDS, branchless float4 main loop.
__global__ __launch_bounds__(256) void k3_pool(
    const float* __restrict__ audio,
    const int* __restrict__ tok0, const float* __restrict__ w0a,
    const int* __restrict__ tok1, const float* __restrict__ w1a,
    const int* __restrict__ lo, const int* __restrict__ hi,
    u16* __restrict__ h1b)
{
    __shared__ float wl[1536];
    const int bm = blockIdx.x;
    const int b = bm / MTOK, m = bm % MTOK;
    const int l = lo[bm], h = hi[bm];
    const int tid = threadIdx.x;
    const int len = h - l;

    // stage combined weights (coalesced; removes scalar-load latency from loop)
    for (int j = tid; j < len; j += 256) {
        int i0 = b*T_ + l + j;
        float w = 0.f;
        if (tok0[i0] == m) w += w0a[i0];
        if (tok1[i0] == m) w += w1a[i0];
        wl[j] = w;
    }
    __syncthreads();

    const int d4 = tid * 4;          // covers 0..1023
    const int d1 = 1024 + tid;       // covers 1024..1279
    const float* rowp = audio + (size_t)(b*T_ + l) * H_;
    float4 acc4 = make_float4(0.f, 0.f, 0.f, 0.f);
    float acc1 = 0.f;
    #pragma unroll 4
    for (int j = 0; j < len; ++j) {
        float w = wl[j];
        const float* row = rowp + (size_t)j * H_;
        float4 r4 = *(const float4*)(row + d4);     // aligned: row stride 5120 B
        float r1 = (d1 < HM1) ? row[d1] : 0.f;
        acc4.x += w * r4.x; acc4.y += w * r4.y;
        acc4.z += w * r4.z; acc4.w += w * r4.w;
        acc1 += w * r1;
    }
    u16* dst = h1b + (size_t)bm * KPAD;
    ushort4 o;
    o.x = f2bf(acc4.x); o.y = f2bf(acc4.y); o.z = f2bf(acc4.z); o.w = f2bf(acc4.w);
    *(ushort4*)&dst[d4] = o;
    dst[d1] = (d1 < HM1) ? f2bf(acc1) : (u16)0;     // d1==1279 -> zero pad
}

// MFMA bf16 GEMM (B^T form), BK=32, 2-phase double-buffered K-loop (T3-min):
// issue next K-step's global_load_lds into the alternate LDS buffer BEFORE
// ds_read+MFMA of the current step; single __syncthreads per step (its
// vmcnt(0) drain lands after a full step of compute -> latency overlapped).
// CIF mode: bf16 out + per-row sum-of-squares atomics (pre-rounding fp32).
// TEXT mode: fp32 out, per-row 1/rms scale applied to acc (rms_w folded in Bt).
template<int TM, bool CIF>
__global__ __launch_bounds__(256, 3) void mfma_gemm_bt(
    const u16* __restrict__ A, const u16* __restrict__ Bt,
    const float* __restrict__ bias, void* __restrict__ Cv,
    float* __restrict__ h_sumsq, int M, int N)
{
    constexpr int K = KPAD;
    constexpr int NT = K / 32;          // 40 K-steps (even)
    constexpr int RA = TM / 64;
    constexpr int MI = 4;
    constexpr int NI = (TM == 128) ? 4 : 2;
    __shared__ u16 sA[2][TM*32];
    __shared__ u16 sB[2][128*32];
    const int tid = threadIdx.x;
    const int m0 = blockIdx.y * TM, n0 = blockIdx.x * 128;
    const int wave = tid >> 6, lane = tid & 63;
    const int wm = (TM == 128) ? (wave & 1) * 64 : 0;
    const int wn = (TM == 128) ? (wave >> 1) * 64 : wave * 32;
    const int lrow = lane & 15, quad = lane >> 4;

    const int r0 = tid >> 2, sl = tid & 3;
    const int q0 = sl ^ (r0 & 3) ^ ((r0 >> 2) & 3);
    const u16* Ag[RA];
    #pragma unroll
    for (int p = 0; p < RA; ++p)
        Ag[p] = A + (size_t)min(m0 + r0 + 64*p, M - 1) * K + q0 * 8;
    const u16* Bg[2];
    #pragma unroll
    for (int p = 0; p < 2; ++p)
        Bg[p] = Bt + (size_t)(n0 + r0 + 64*p) * K + q0 * 8;

    int offA[MI], offB[NI];
    #pragma unroll
    for (int i = 0; i < MI; ++i) {
        int m = wm + i*16 + lrow;
        offA[i] = m*32 + (quad ^ (m & 3) ^ ((m >> 2) & 3)) * 8;
    }
    #pragma unroll
    for (int i = 0; i < NI; ++i) {
        int n = wn + i*16 + lrow;
        offB[i] = n*32 + (quad ^ (n & 3) ^ ((n >> 2) & 3)) * 8;
    }

    f32x4 acc[MI][NI] = {};

    // prologue: stage K-step 0 into buffer 0, drain, barrier
    #pragma unroll
    for (int p = 0; p < RA; ++p) glds16(Ag[p], &sA[0][(tid + 256*p)*8]);
    #pragma unroll
    for (int p = 0; p < 2;  ++p) glds16(Bg[p], &sB[0][(tid + 256*p)*8]);
    __syncthreads();

    for (int t = 0; t < NT; t += 2) {
        // ---- even step: stage t+1 -> buf1, compute from buf0 ----
        {
            const int k1 = (t + 1) * 32;    // t+1 <= NT-1 always (NT even)
            #pragma unroll
            for (int p = 0; p < RA; ++p) glds16(Ag[p] + k1, &sA[1][(tid + 256*p)*8]);
            #pragma unroll
            for (int p = 0; p < 2;  ++p) glds16(Bg[p] + k1, &sB[1][(tid + 256*p)*8]);
            bf16x8 af[MI], bfr[NI];
            #pragma unroll
            for (int i = 0; i < MI; ++i) af[i]  = *(const bf16x8*)&sA[0][offA[i]];
            #pragma unroll
            for (int i = 0; i < NI; ++i) bfr[i] = *(const bf16x8*)&sB[0][offB[i]];
            #pragma unroll
            for (int mi = 0; mi < MI; ++mi)
                #pragma unroll
                for (int ni = 0; ni < NI; ++ni)
                    acc[mi][ni] = __builtin_amdgcn_mfma_f32_16x16x32_bf16(
                        af[mi], bfr[ni], acc[mi][ni], 0, 0, 0);
            __syncthreads();   // drains vmcnt(0): buf1 ready; all reads of buf0 done
        }
        // ---- odd step: stage t+2 -> buf0 (if any), compute from buf1 ----
        {
            const int k2 = (t + 2) * 32;
            if (t + 2 < NT) {
                #pragma unroll
                for (int p = 0; p < RA; ++p) glds16(Ag[p] + k2, &sA[0][(tid + 256*p)*8]);
                #pragma unroll
                for (int p = 0; p < 2;  ++p) glds16(Bg[p] + k2, &sB[0][(tid + 256*p)*8]);
            }
            bf16x8 af[MI], bfr[NI];
            #pragma unroll
            for (int i = 0; i < MI; ++i) af[i]  = *(const bf16x8*)&sA[1][offA[i]];
            #pragma unroll
            for (int i = 0; i < NI; ++i) bfr[i] = *(const bf16x8*)&sB[1][offB[i]];
            #pragma unroll
            for (int mi = 0; mi < MI; ++mi)
                #pragma unroll
                for (int ni = 0; ni < NI; ++ni)
                    acc[mi][ni] = __builtin_amdgcn_mfma_f32_16x16x32_bf16(
                        af[mi], bfr[ni], acc[mi][ni], 0, 0, 0);
            __syncthreads();
        }
    }

    // epilogue: C/D layout col=lane&15, row=quad*4+reg
    float bv[NI];
    #pragma unroll
    for (int ni = 0; ni < NI; ++ni) bv[ni] = bias[n0 + wn + ni*16 + lrow];

    #pragma unroll
    for (int mi = 0; mi < MI; ++mi) {
        #pragma unroll
        for (int r = 0; r < 4; ++r) {
            int row = m0 + wm + mi*16 + quad*4 + r;
            if (CIF) {
                float ss = 0.f;
                #pragma unroll
                for (int ni = 0; ni < NI; ++ni) {
                    float v = acc[mi][ni][r] + bv[ni];
                    ss += v * v;
                    if (row < M)
                        ((u16*)Cv)[(size_t)row*N + (n0 + wn + ni*16 + lrow)] = f2bf(v);
                }
                // reduce ss over the 16 lanes (lrow) sharing this row
                ss += __shfl_xor(ss, 1);
                ss += __shfl_xor(ss, 2);
                ss += __shfl_xor(ss, 4);
                ss += __shfl_xor(ss, 8);
                if (lrow == 0 && row < M) atomicAdd(&h_sumsq[row], ss);
            } else {
                float inv = 1.f;
                if (row < M)
                    inv = 1.f / sqrtf(h_sumsq[row] / (float)H_ + 1e-6f);
                #pragma unroll
                for (int ni = 0; ni < NI; ++ni) {
                    if (row < M)
                        ((float*)Cv)[(size_t)row*N + (n0 + wn + ni*16 + lrow)] =
                            acc[mi][ni][r] * inv + bv[ni];
                }
            }
        }
    }
}

extern "C" void kernel_launch(void* const* d_in, const int* in_sizes, int n_in,
                              void* d_out, int out_size, void* d_ws, size_t ws_size,
                              hipStream_t stream) {
    (void)in_sizes; (void)n_in; (void)out_size; (void)ws_size;
    const float* audio      = (const float*)d_in[0];
    const int*   num_tokens = (const int*)d_in[1];
    const float* rms_w      = (const float*)d_in[2];
    const float* cif_w      = (const float*)d_in[3];
    const float* cif_b      = (const float*)d_in[4];
    const float* text_w     = (const float*)d_in[5];
    const float* text_b     = (const float*)d_in[6];

    float* out  = (float*)d_out;                   // fp32 output
    float* pred = out + (size_t)MROWS * OUT_;      // pred_num_tokens tail (8 floats)

    char* ws = (char*)d_ws;
    float* h_sumsq = (float*)(ws + 0);         // 12000 B (zeroed in k_front)
    float* w0a  = (float*)(ws + 48000);
    float* w1a  = (float*)(ws + 96000);
    int*   tok0 = (int*)  (ws + 144000);
    int*   tok1 = (int*)  (ws + 192000);
    int*   lo   = (int*)  (ws + 240000);
    int*   hi   = (int*)  (ws + 252000);
    // DISJOINT regions (no lifetime aliasing):
    u16* h1b = (u16*)(ws + 264192);     //  7,680,000 B
    u16* cwt = (u16*)(ws + 7944192);    //  3,276,800 B
    u16* twt = (u16*)(ws + 11220992);   // 10,485,760 B  (rms_w folded in)
    u16* hX  = (u16*)(ws + 21706752);   //  7,680,000 B  (cif out, unnormalized)
    // total ws usage: 29,386,752 B

    // scan (blocks 0..7) + weight transposes (blocks 8..6727)
    k_front<<<B_ + 1600 + 5120, 256, 0, stream>>>(
        audio, num_tokens, rms_w, pred, tok0, w0a, tok1, w1a, lo, hi,
        h_sumsq, cif_w, text_w, cwt, twt);
    k3_pool<<<MROWS, 256, 0, stream>>>(audio, tok0, w0a, tok1, w1a, lo, hi, h1b);
    // cif_proj (bf16 out + row sumsq): hX = h1b . cwt^T + cif_b
    mfma_gemm_bt<64, true><<<dim3(H_/128, (MROWS+63)/64), 256, 0, stream>>>(
        h1b, cwt, cif_b, hX, h_sumsq, MROWS, H_);
    // text_proj (fp32 out, 1/rms applied in epilogue): out = norm(hX) . twt^T + text_b
    mfma_gemm_bt<128, false><<<dim3(OUT_/128, (MROWS+127)/128), 256, 0, stream>>>(
        hX, twt, text_b, out, h_sumsq, MROWS, OUT_);
}

// Round 2
// 237.513 us; speedup vs baseline: 1.0536x; 1.0536x over previous
//
#include <hip/hip_runtime.h>
#include <hip/hip_bf16.h>
#include <stdint.h>

// Problem constants (from reference)
#define B_ 8
#define T_ 1500
#define TPAD 1504         // T_ padded to multiple of 16 for the scan batcher
#define H_ 1280
#define HM1 1279
#define OUT_ 4096
#define MTOK 375
#define MROWS (B_*MTOK)   // 3000
#define KPAD 1280         // shared K for both GEMMs (cif K=1279 zero-padded)

typedef __attribute__((ext_vector_type(8))) short bf16x8;  // 8 bf16 = 4 VGPRs
typedef __attribute__((ext_vector_type(4))) float f32x4;
typedef unsigned short u16;

static __device__ __forceinline__ u16 f2bf(float f) {
    unsigned int x = __float_as_uint(f);
    unsigned int r = (x + 0x7fffu + ((x >> 16) & 1u)) >> 16;
    return (u16)r;
}
static __device__ __forceinline__ void glds16(const u16* g, u16* l) {
    __builtin_amdgcn_global_load_lds(
        (const __attribute__((address_space(1))) void*)g,
        (__attribute__((address_space(3))) void*)l, 16, 0, 0);
}

// Front kernel: blocks 0..7 = fused sigmoid+scan+post-pass (one per batch);
// blocks 8.. = both weight transposes (text transpose folds in rms_w).
__global__ __launch_bounds__(256) void k_front(
    const float* __restrict__ audio, const int* __restrict__ num_tokens,
    const float* __restrict__ rms_w,
    float* __restrict__ pred_out,
    int* __restrict__ tok0, float* __restrict__ w0a,
    int* __restrict__ tok1, float* __restrict__ w1a,
    int* __restrict__ lo, int* __restrict__ hi,
    float* __restrict__ h_sumsq,
    const float* __restrict__ cif_w, const float* __restrict__ text_w,
    u16* __restrict__ cwt, u16* __restrict__ twt)
{
    __shared__ float smem[3524];   // union: scan(3521 floats) / transpose tile(32x33)
    const int tid = threadIdx.x;

    if (blockIdx.x < B_) {
        // ================= CIF scan branch =================
        const int b = blockIdx.x;
        float* al = smem;                    // [1504] (1500 + 4 zero pad)
        float* ip = smem + TPAD;             // [1504]
        float* red = smem + 2*TPAD;          // [256]
        int*   redI = (int*)(smem + 2*TPAD + 256);   // [256]
        float* scale_sh = smem + 2*TPAD + 512;

        // phase 1: sigmoid + pred + scale
        float sig[6];
        float s = 0.f;
        #pragma unroll
        for (int i = 0; i < 6; ++i) {
            int t = tid + i*256;
            sig[i] = 0.f;
            if (t < T_) {
                float x = audio[((size_t)b*T_ + t)*H_ + (H_-1)];
                sig[i] = 1.f / (1.f + expf(-x));
                s += sig[i];
            }
        }
        red[tid] = s; __syncthreads();
        for (int off = 128; off > 0; off >>= 1) {
            if (tid < off) red[tid] += red[tid+off];
            __syncthreads();
        }
        if (tid == 0) {
            float pred = red[0];
            pred_out[b] = pred;
            *scale_sh = (float)num_tokens[b] / pred;
        }
        __syncthreads();
        float scale = *scale_sh;
        #pragma unroll
        for (int i = 0; i < 6; ++i) {
            int t = tid + i*256;
            if (t < T_) al[t] = sig[i] * scale;
        }
        if (tid < TPAD - T_) al[T_ + tid] = 0.f;   // zero pad for batch-16 scan
        for (int m = tid; m < MTOK; m += 256) {
            lo[b*MTOK+m] = T_; hi[b*MTOK+m] = 0;
            h_sumsq[b*MTOK+m] = 0.f;         // zero for cif-epilogue atomics
        }
        if (tid == 0) lo[b*MTOK] = 0;
        __syncthreads();

        // phase 2: serial carry chain (lane 0), batch-16 double-buffered LDS
        // loads (hides ~120cy ds_read latency) + 2-op dep chain:
        // integ' = sx - floor(sx)  ==bitwise==  (sx>=1 ? sx-1 : sx) for sx in [0,2)
        if (tid == 0) {
            float integ = 0.f;
            float4 c0 = *(const float4*)&al[0];
            float4 c1 = *(const float4*)&al[4];
            float4 c2 = *(const float4*)&al[8];
            float4 c3 = *(const float4*)&al[12];
            for (int t = 0; t < TPAD; t += 16) {
                float4 n0, n1, n2, n3;
                if (t + 16 < TPAD) {
                    n0 = *(const float4*)&al[t+16];
                    n1 = *(const float4*)&al[t+20];
                    n2 = *(const float4*)&al[t+24];
                    n3 = *(const float4*)&al[t+28];
                }
                float4 o0, o1, o2, o3;
                float sx;
                o0.x = integ; sx = integ + c0.x; integ = sx - floorf(sx);
                o0.y = integ; sx = integ + c0.y; integ = sx - floorf(sx);
                o0.z = integ; sx = integ + c0.z; integ = sx - floorf(sx);
                o0.w = integ; sx = integ + c0.w; integ = sx - floorf(sx);
                o1.x = integ; sx = integ + c1.x; integ = sx - floorf(sx);
                o1.y = integ; sx = integ + c1.y; integ = sx - floorf(sx);
                o1.z = integ; sx = integ + c1.z; integ = sx - floorf(sx);
                o1.w = integ; sx = integ + c1.w; integ = sx - floorf(sx);
                o2.x = integ; sx = integ + c2.x; integ = sx - floorf(sx);
                o2.y = integ; sx = integ + c2.y; integ = sx - floorf(sx);
                o2.z = integ; sx = integ + c2.z; integ = sx - floorf(sx);
                o2.w = integ; sx = integ + c2.w; integ = sx - floorf(sx);
                o3.x = integ; sx = integ + c3.x; integ = sx - floorf(sx);
                o3.y = integ; sx = integ + c3.y; integ = sx - floorf(sx);
                o3.z = integ; sx = integ + c3.z; integ = sx - floorf(sx);
                o3.w = integ; sx = integ + c3.w; integ = sx - floorf(sx);
                *(float4*)&ip[t+0]  = o0;
                *(float4*)&ip[t+4]  = o1;
                *(float4*)&ip[t+8]  = o2;
                *(float4*)&ip[t+12] = o3;
                c0 = n0; c1 = n1; c2 = n2; c3 = n3;
            }
        }
        __syncthreads();

        // phase 3: parallel post-pass
        const int t0 = tid * 6;
        const int nm1 = num_tokens[b] - 1;
        int fires[6];
        int cnt = 0;
        if (t0 < T_) {
            #pragma unroll
            for (int j = 0; j < 6; ++j) {
                int t = t0 + j;
                float sx = ip[t] + al[t];     // same fp32 add as serial scan
                fires[j] = (sx >= 1.f) ? 1 : 0;
                cnt += fires[j];
            }
        }
        redI[tid] = cnt; __syncthreads();
        #pragma unroll
        for (int off = 1; off < 256; off <<= 1) {
            int v = redI[tid];
            if (tid >= off) v += redI[tid - off];
            __syncthreads();
            redI[tid] = v;
            __syncthreads();
        }
        if (t0 < T_) {
            int F = redI[tid] - cnt;
            const int base = b*T_;
            #pragma unroll
            for (int j = 0; j < 6; ++j) {
                int t = t0 + j;
                float a = al[t], ipv = ip[t];
                int fire = fires[j];
                F += fire;
                int tk1 = min(F, nm1);
                int tk0 = min(F - fire, nm1);
                float w0 = fire ? (1.f - ipv) : a;
                float w1 = (t < T_-1) ? (a - w0) : 0.f;
                tok0[base+t] = tk0;  w0a[base+t] = w0;
                tok1[base+t] = tk1;  w1a[base+t] = w1;
                if (tk1 != tk0) {
                    hi[b*MTOK + tk0] = t + 1;
                    lo[b*MTOK + tk1] = t;
                }
                if (t == T_-1) hi[b*MTOK + tk1] = T_;
            }
        }
    } else {
        // ================= transpose branch =================
        float (*tile)[33] = (float(*)[33])smem;
        int blk = blockIdx.x - B_;
        const float* src; u16* dst; int R, C, bx, by; bool scaled;
        if (blk < 1600) { src = cif_w;  dst = cwt; R = HM1; C = H_;   bx = blk % 40;  by = blk / 40;  scaled = false; }
        else { blk -= 1600; src = text_w; dst = twt; R = H_;  C = OUT_; bx = blk % 128; by = blk / 128; scaled = true; }
        int c0 = bx * 32, r0 = by * 32;
        int lx = tid & 31, ly = tid >> 5;  // 32 x 8
        #pragma unroll
        for (int j = 0; j < 4; ++j) {
            int r = r0 + ly + j*8;
            tile[ly + j*8][lx] = (r < R) ? src[(size_t)r*C + c0 + lx] : 0.f;
        }
        __syncthreads();
        // write value = src[r0+lx][c0+ly+j*8]; its k-index is r0+lx -> fold rms_w
        float rw = scaled ? rms_w[r0 + lx] : 1.f;
        #pragma unroll
        for (int j = 0; j < 4; ++j) {
            int c = c0 + ly + j*8;
            dst[(size_t)c*KPAD + r0 + lx] = f2bf(tile[lx][ly + j*8] * rw);
        }
    }
}

// K3: sparse pooling -> h1b bf16 [MROWS][KPAD], col 1279 = 0.
// Latency-optimized: weights staged to LDS, branchless float4 main loop.
__global__ __launch_bounds__(256) void k3_pool(
    const float* __restrict__ audio,
    const int* __restrict__ tok0, const float* __restrict__ w0a,
    const int* __restrict__ tok1, const float* __restrict__ w1a,
    const int* __restrict__ lo, const int* __restrict__ hi,
    u16* __restrict__ h1b)
{
    __shared__ float wl[1536];
    const int bm = blockIdx.x;
    const int b = bm / MTOK, m = bm % MTOK;
    const int l = lo[bm], h = hi[bm];
    const int tid = threadIdx.x;
    const int len = h - l;

    // stage combined weights (coalesced; removes scalar-load latency from loop)
    for (int j = tid; j < len; j += 256) {
        int i0 = b*T_ + l + j;
        float w = 0.f;
        if (tok0[i0] == m) w += w0a[i0];
        if (tok1[i0] == m) w += w1a[i0];
        wl[j] = w;
    }
    __syncthreads();

    const int d4 = tid * 4;          // covers 0..1023
    const int d1 = 1024 + tid;       // covers 1024..1279
    const float* rowp = audio + (size_t)(b*T_ + l) * H_;
    float4 acc4 = make_float4(0.f, 0.f, 0.f, 0.f);
    float acc1 = 0.f;
    #pragma unroll 4
    for (int j = 0; j < len; ++j) {
        float w = wl[j];
        const float* row = rowp + (size_t)j * H_;
        float4 r4 = *(const float4*)(row + d4);     // aligned: row stride 5120 B
        float r1 = (d1 < HM1) ? row[d1] : 0.f;
        acc4.x += w * r4.x; acc4.y += w * r4.y;
        acc4.z += w * r4.z; acc4.w += w * r4.w;
        acc1 += w * r1;
    }
    u16* dst = h1b + (size_t)bm * KPAD;
    ushort4 o;
    o.x = f2bf(acc4.x); o.y = f2bf(acc4.y); o.z = f2bf(acc4.z); o.w = f2bf(acc4.w);
    *(ushort4*)&dst[d4] = o;
    dst[d1] = (d1 < HM1) ? f2bf(acc1) : (u16)0;     // d1==1279 -> zero pad
}

// MFMA bf16 GEMM (B^T form), BK=32, 3-stage ring + counted vmcnt (T3/T4):
// one raw s_barrier per K-step; s_waitcnt vmcnt(LPT) keeps the next 1-2
// stages' global_load_lds in flight ACROSS the barrier (never drains to 0
// in-loop). Slot overwrite safety: stage t+2 is issued only after barrier t,
// and every wave's ds_reads of stage t-1 drained (lgkmcnt before its MFMAs)
// before it reached barrier t.  T5: setprio(1) around the MFMA cluster.
// CIF mode: bf16 out + per-row sum-of-squares atomics (pre-rounding fp32).
// TEXT mode: fp32 out, per-row 1/rms scale applied to acc (rms_w folded in Bt).
#define WAITVM(N) asm volatile("s_waitcnt vmcnt(" #N ")" ::: "memory")

template<int TM, bool CIF>
__global__ __launch_bounds__(256, 3) void mfma_gemm_bt(
    const u16* __restrict__ A, const u16* __restrict__ Bt,
    const float* __restrict__ bias, void* __restrict__ Cv,
    float* __restrict__ h_sumsq, int M, int N)
{
    constexpr int K = KPAD;
    constexpr int NT = K / 32;          // 40 K-steps
    constexpr int RA = TM / 64;         // A-loads per thread per stage
    constexpr int MI = 4;
    constexpr int NI = (TM == 128) ? 4 : 2;
    __shared__ u16 sA[3][TM*32];
    __shared__ u16 sB[3][128*32];
    const int tid = threadIdx.x;
    const int m0 = blockIdx.y * TM, n0 = blockIdx.x * 128;
    const int wave = tid >> 6, lane = tid & 63;
    const int wm = (TM == 128) ? (wave & 1) * 64 : 0;
    const int wn = (TM == 128) ? (wave >> 1) * 64 : wave * 32;
    const int lrow = lane & 15, quad = lane >> 4;

    const int r0 = tid >> 2, sl = tid & 3;
    const int q0 = sl ^ (r0 & 3) ^ ((r0 >> 2) & 3);
    const u16* Ag[RA];
    #pragma unroll
    for (int p = 0; p < RA; ++p)
        Ag[p] = A + (size_t)min(m0 + r0 + 64*p, M - 1) * K + q0 * 8;
    const u16* Bg[2];
    #pragma unroll
    for (int p = 0; p < 2; ++p)
        Bg[p] = Bt + (size_t)(n0 + r0 + 64*p) * K + q0 * 8;

    int offA[MI], offB[NI];
    #pragma unroll
    for (int i = 0; i < MI; ++i) {
        int m = wm + i*16 + lrow;
        offA[i] = m*32 + (quad ^ (m & 3) ^ ((m >> 2) & 3)) * 8;
    }
    #pragma unroll
    for (int i = 0; i < NI; ++i) {
        int n = wn + i*16 + lrow;
        offB[i] = n*32 + (quad ^ (n & 3) ^ ((n >> 2) & 3)) * 8;
    }

    // rotating stage pointers (cur / next / future), kept in registers
    u16 *Ac = sA[0], *An = sA[1], *Af = sA[2];
    u16 *Bc = sB[0], *Bn = sB[1], *Bf = sB[2];

    auto stage = [&](int kk, u16* da, u16* db) {
        #pragma unroll
        for (int p = 0; p < RA; ++p) glds16(Ag[p] + kk, da + (tid + 256*p)*8);
        #pragma unroll
        for (int p = 0; p < 2;  ++p) glds16(Bg[p] + kk, db + (tid + 256*p)*8);
    };

    f32x4 acc[MI][NI] = {};

    // prologue: stages 0 and 1 in flight
    stage(0,  Ac, Bc);
    stage(32, An, Bn);

    for (int t = 0; t < NT - 1; ++t) {
        // retire stage t's loads (LPT = RA+2 per stage still in flight beyond)
        if constexpr (TM == 128) WAITVM(4); else WAITVM(3);
        __builtin_amdgcn_s_barrier();          // all waves: stage t ready
        asm volatile("" ::: "memory");         // no LDS reads hoisted above
        if (t + 2 < NT) stage((t + 2) * 32, Af, Bf);   // overwrite slot t-1 (safe)
        bf16x8 af[MI], bfr[NI];
        #pragma unroll
        for (int i = 0; i < MI; ++i) af[i]  = *(const bf16x8*)&Ac[offA[i]];
        #pragma unroll
        for (int i = 0; i < NI; ++i) bfr[i] = *(const bf16x8*)&Bc[offB[i]];
        __builtin_amdgcn_s_setprio(1);
        #pragma unroll
        for (int mi = 0; mi < MI; ++mi)
            #pragma unroll
            for (int ni = 0; ni < NI; ++ni)
                acc[mi][ni] = __builtin_amdgcn_mfma_f32_16x16x32_bf16(
                    af[mi], bfr[ni], acc[mi][ni], 0, 0, 0);
        __builtin_amdgcn_s_setprio(0);
        u16* ta = Ac; Ac = An; An = Af; Af = ta;
        u16* tb = Bc; Bc = Bn; Bn = Bf; Bf = tb;
    }
    {   // final K-step: only stage NT-1 outstanding
        WAITVM(0);
        __builtin_amdgcn_s_barrier();
        asm volatile("" ::: "memory");
        bf16x8 af[MI], bfr[NI];
        #pragma unroll
        for (int i = 0; i < MI; ++i) af[i]  = *(const bf16x8*)&Ac[offA[i]];
        #pragma unroll
        for (int i = 0; i < NI; ++i) bfr[i] = *(const bf16x8*)&Bc[offB[i]];
        __builtin_amdgcn_s_setprio(1);
        #pragma unroll
        for (int mi = 0; mi < MI; ++mi)
            #pragma unroll
            for (int ni = 0; ni < NI; ++ni)
                acc[mi][ni] = __builtin_amdgcn_mfma_f32_16x16x32_bf16(
                    af[mi], bfr[ni], acc[mi][ni], 0, 0, 0);
        __builtin_amdgcn_s_setprio(0);
    }

    // epilogue: C/D layout col=lane&15, row=quad*4+reg
    float bv[NI];
    #pragma unroll
    for (int ni = 0; ni < NI; ++ni) bv[ni] = bias[n0 + wn + ni*16 + lrow];

    #pragma unroll
    for (int mi = 0; mi < MI; ++mi) {
        #pragma unroll
        for (int r = 0; r < 4; ++r) {
            int row = m0 + wm + mi*16 + quad*4 + r;
            if (CIF) {
                float ss = 0.f;
                #pragma unroll
                for (int ni = 0; ni < NI; ++ni) {
                    float v = acc[mi][ni][r] + bv[ni];
                    ss += v * v;
                    if (row < M)
                        ((u16*)Cv)[(size_t)row*N + (n0 + wn + ni*16 + lrow)] = f2bf(v);
                }
                // reduce ss over the 16 lanes (lrow) sharing this row
                ss += __shfl_xor(ss, 1);
                ss += __shfl_xor(ss, 2);
                ss += __shfl_xor(ss, 4);
                ss += __shfl_xor(ss, 8);
                if (lrow == 0 && row < M) atomicAdd(&h_sumsq[row], ss);
            } else {
                float inv = 1.f;
                if (row < M)
                    inv = 1.f / sqrtf(h_sumsq[row] / (float)H_ + 1e-6f);
                #pragma unroll
                for (int ni = 0; ni < NI; ++ni) {
                    if (row < M)
                        ((float*)Cv)[(size_t)row*N + (n0 + wn + ni*16 + lrow)] =
                            acc[mi][ni][r] * inv + bv[ni];
                }
            }
        }
    }
}

extern "C" void kernel_launch(void* const* d_in, const int* in_sizes, int n_in,
                              void* d_out, int out_size, void* d_ws, size_t ws_size,
                              hipStream_t stream) {
    (void)in_sizes; (void)n_in; (void)out_size; (void)ws_size;
    const float* audio      = (const float*)d_in[0];
    const int*   num_tokens = (const int*)d_in[1];
    const float* rms_w      = (const float*)d_in[2];
    const float* cif_w      = (const float*)d_in[3];
    const float* cif_b      = (const float*)d_in[4];
    const float* text_w     = (const float*)d_in[5];
    const float* text_b     = (const float*)d_in[6];

    float* out  = (float*)d_out;                   // fp32 output
    float* pred = out + (size_t)MROWS * OUT_;      // pred_num_tokens tail (8 floats)

    char* ws = (char*)d_ws;
    float* h_sumsq = (float*)(ws + 0);         // 12000 B (zeroed in k_front)
    float* w0a  = (float*)(ws + 48000);
    float* w1a  = (float*)(ws + 96000);
    int*   tok0 = (int*)  (ws + 144000);
    int*   tok1 = (int*)  (ws + 192000);
    int*   lo   = (int*)  (ws + 240000);
    int*   hi   = (int*)  (ws + 252000);
    // DISJOINT regions (no lifetime aliasing):
    u16* h1b = (u16*)(ws + 264192);     //  7,680,000 B
    u16* cwt = (u16*)(ws + 7944192);    //  3,276,800 B
    u16* twt = (u16*)(ws + 11220992);   // 10,485,760 B  (rms_w folded in)
    u16* hX  = (u16*)(ws + 21706752);   //  7,680,000 B  (cif out, unnormalized)
    // total ws usage: 29,386,752 B

    // scan (blocks 0..7) + weight transposes (blocks 8..6727)
    k_front<<<B_ + 1600 + 5120, 256, 0, stream>>>(
        audio, num_tokens, rms_w, pred, tok0, w0a, tok1, w1a, lo, hi,
        h_sumsq, cif_w, text_w, cwt, twt);
    k3_pool<<<MROWS, 256, 0, stream>>>(audio, tok0, w0a, tok1, w1a, lo, hi, h1b);
    // cif_proj (bf16 out + row sumsq): hX = h1b . cwt^T + cif_b
    mfma_gemm_bt<64, true><<<dim3(H_/128, (MROWS+63)/64), 256, 0, stream>>>(
        h1b, cwt, cif_b, hX, h_sumsq, MROWS, H_);
    // text_proj (fp32 out, 1/rms applied in epilogue): out = norm(hX) . twt^T + text_b
    mfma_gemm_bt<128, false><<<dim3(OUT_/128, (MROWS+127)/128), 256, 0, stream>>>(
        hX, twt, text_b, out, h_sumsq, MROWS, OUT_);
}